// Round 5
// baseline (273.338 us; speedup 1.0000x reference)
//
#include <hip/hip_runtime.h>
#include <stdint.h>

#define C_IN 256
#define C_MID 64
#define KOFF 9

typedef __attribute__((ext_vector_type(8))) short bf16x8;   // 8 bf16 = 4 VGPRs
typedef __attribute__((ext_vector_type(4))) short short4v;  // 8 B packed bf16x4
typedef __attribute__((ext_vector_type(4))) float f32x4;    // MFMA C/D
typedef __attribute__((ext_vector_type(4))) float float4v;

// fp32 -> bf16 round-to-nearest-even
__device__ inline unsigned short f2bf(float f) {
    union { float f; unsigned u; } x; x.f = f;
    unsigned r = x.u + 0x7FFFu + ((x.u >> 16) & 1u);
    return (unsigned short)(r >> 16);
}

// ---------------------------------------------------------------------------
// prep (unchanged):
//   w1t[n][k] = bf16(w1[k][n] * s1[n])          [64][256]   16384 shorts
//   w2t[k][d][c] = bf16(w2[k][c][d] * s2[d])    [9][64][64] 36864 shorts
//   w3t[e][c] = bf16(w3[c][e] * s3[e])          [256][64]   16384 shorts
// ---------------------------------------------------------------------------
__global__ void prep_kernel(const float* __restrict__ w1, const float* __restrict__ s1,
                            const float* __restrict__ w2, const float* __restrict__ s2,
                            const float* __restrict__ w3, const float* __restrict__ s3,
                            unsigned short* __restrict__ w1t,
                            unsigned short* __restrict__ w2t,
                            unsigned short* __restrict__ w3t,
                            unsigned short* __restrict__ zrow) {
    int tid = blockIdx.x * blockDim.x + threadIdx.x;
    int stride = gridDim.x * blockDim.x;
    for (int i = tid; i < C_MID * C_IN; i += stride) {
        int n = i / C_IN, k = i % C_IN;
        w1t[i] = f2bf(w1[k * C_MID + n] * s1[n]);
    }
    for (int i = tid; i < KOFF * C_MID * C_MID; i += stride) {
        int k = i / (C_MID * C_MID);
        int r = i % (C_MID * C_MID);
        int d = r / C_MID, c = r % C_MID;
        w2t[i] = f2bf(w2[(k * C_MID + c) * C_MID + d] * s2[d]);
    }
    for (int i = tid; i < C_IN * C_MID; i += stride) {
        int e = i / C_MID, c = i % C_MID;
        w3t[i] = f2bf(w3[c * C_IN + e] * s3[e]);
    }
    for (int i = tid; i < C_MID; i += stride) zrow[i] = 0;
}

// ---------------------------------------------------------------------------
// conv1 v4 (R0 verbatim — part of the 260.7 µs baseline): role-swapped,
// LDS = sW1 only (32.8 KB -> 4 blocks/CU). fr loads split into two pinned
// groups of 8 float4 (peak ~95 regs <= 128 cap, no spill).
// ---------------------------------------------------------------------------
__global__ __launch_bounds__(256, 4) void conv1_kernel(
    const float* __restrict__ feat, const unsigned short* __restrict__ w1t,
    const float* __restrict__ b1, unsigned short* __restrict__ out1, int N)
{
    __shared__ __align__(16) unsigned short sW1[16384];      // 32768 B

    int t = threadIdx.x;
    int wave = t >> 6;
    int lane = t & 63;
    int l15 = lane & 15;
    int quad = lane >> 4;
    int site = blockIdx.x * 64 + wave * 16 + l15;
    int sitec = site < N ? site : (N - 1);

    const bf16x8* w1c = reinterpret_cast<const bf16x8*>(w1t);
    bf16x8* sW1c = reinterpret_cast<bf16x8*>(sW1);
#pragma unroll
    for (int it = 0; it < 8; ++it) {
        int s = it * 256 + t;
        int l = s & 15, ct = (s >> 4) & 3, q = (s >> 6) & 3, kk = s >> 8;
        sW1c[s] = w1c[(ct * 16 + l) * 32 + kk * 4 + q];
    }

    // ---- pin group 0: kk = 0..3 (8 float4 = 32 regs) ----
    float4v fr0[8];
#pragma unroll
    for (int kk = 0; kk < 4; ++kk) {
        const float4v* p = reinterpret_cast<const float4v*>(
            feat + (size_t)sitec * C_IN + kk * 32 + quad * 8);
        fr0[kk * 2] = p[0];
        fr0[kk * 2 + 1] = p[1];
    }
    __builtin_amdgcn_sched_barrier(0);
    __syncthreads();

    // ---- pin group 1: kk = 4..7 (in flight during group-0 compute) ----
    float4v fr1[8];
#pragma unroll
    for (int kk = 0; kk < 4; ++kk) {
        const float4v* p = reinterpret_cast<const float4v*>(
            feat + (size_t)sitec * C_IN + (kk + 4) * 32 + quad * 8);
        fr1[kk * 2] = p[0];
        fr1[kk * 2 + 1] = p[1];
    }
    __builtin_amdgcn_sched_barrier(0);

    f32x4 acc[4] = {};
#pragma unroll
    for (int kk = 0; kk < 4; ++kk) {
        union { unsigned short s[8]; bf16x8 v; } ua;
#pragma unroll
        for (int j = 0; j < 4; ++j) {
            ua.s[j] = f2bf(fr0[kk * 2][j]);
            ua.s[4 + j] = f2bf(fr0[kk * 2 + 1][j]);
        }
#pragma unroll
        for (int ct = 0; ct < 4; ++ct) {
            bf16x8 fa = sW1c[((kk * 4 + quad) * 4 + ct) * 16 + l15];
            acc[ct] = __builtin_amdgcn_mfma_f32_16x16x32_bf16(fa, ua.v, acc[ct], 0, 0, 0);
        }
    }
#pragma unroll
    for (int kk = 0; kk < 4; ++kk) {
        union { unsigned short s[8]; bf16x8 v; } ua;
#pragma unroll
        for (int j = 0; j < 4; ++j) {
            ua.s[j] = f2bf(fr1[kk * 2][j]);
            ua.s[4 + j] = f2bf(fr1[kk * 2 + 1][j]);
        }
#pragma unroll
        for (int ct = 0; ct < 4; ++ct) {
            bf16x8 fa = sW1c[(((kk + 4) * 4 + quad) * 4 + ct) * 16 + l15];
            acc[ct] = __builtin_amdgcn_mfma_f32_16x16x32_bf16(fa, ua.v, acc[ct], 0, 0, 0);
        }
    }
    if (site < N) {
#pragma unroll
        for (int ct = 0; ct < 4; ++ct) {
            float4v bb = *reinterpret_cast<const float4v*>(b1 + ct * 16 + quad * 4);
            union { unsigned short s[4]; short4v v; } o;
#pragma unroll
            for (int reg = 0; reg < 4; ++reg)
                o.s[reg] = f2bf(fmaxf(acc[ct][reg] + bb[reg], 0.f));
            *reinterpret_cast<short4v*>(out1 + (size_t)site * C_MID + ct * 16 + quad * 4) = o.v;
        }
    }
}

// ---------------------------------------------------------------------------
// conv23 v8: fused (no mid global round trip), 4 blocks/CU.
// LDS = sW2 3-phase (24576 B) + sMid (9216 B) + sNbr (2304 B) = 36096 B.
// w3 fragments read DIRECTLY from L2/L1 (no stage, no extra barrier; each
// wave's 32 KB w3 stream is L1-resident after the first wave; addressing
// proven numerically correct in R1/R4 runs). rf pinned after conv2 (ga dead)
// so its 64 regs drain during the mid-RAW barrier. (256,3): cap ~170, the
// proven budget for the 72-reg ga pin set.
// ---------------------------------------------------------------------------
__global__ __launch_bounds__(256, 3) void conv23_kernel(
    const float* __restrict__ feat, const int* __restrict__ nbr,
    const unsigned short* __restrict__ out1, const unsigned short* __restrict__ w2t,
    const float* __restrict__ b2, const unsigned short* __restrict__ w3t,
    const float* __restrict__ b3, float* __restrict__ out, int N)
{
    __shared__ __align__(16) unsigned short sW2[12288];      // 24576 B
    __shared__ __align__(16) unsigned short sMid[64 * 72];   // 9216 B
    __shared__ int sNbr[64 * KOFF];                          // 2304 B

    int t = threadIdx.x;
    int wave = t >> 6;
    int lane = t & 63;
    int l15 = lane & 15;
    int quad = lane >> 4;
    int rt = wave * 16 + l15;
    int site = blockIdx.x * 64 + rt;
    int sitec = site < N ? site : (N - 1);

    bf16x8* sW2c = reinterpret_cast<bf16x8*>(sW2);
    const bf16x8* w2c = reinterpret_cast<const bf16x8*>(w2t);

    // ---- stage w2 phase0 (k=0..2, 1536 chunks, 6/thread) + rulebook ----
#pragma unroll
    for (int it = 0; it < 6; ++it) {
        int s = it * 256 + t;
        int l = s & 15, ct = (s >> 4) & 3, q = (s >> 6) & 3, kk = (s >> 8) & 1, k2 = s >> 9;
        sW2c[s] = w2c[k2 * 512 + (ct * 16 + l) * 8 + kk * 4 + q];
    }
#pragma unroll
    for (int i = 0; i < 3; ++i) {
        int j = i * 256 + t;
        if (j < 64 * KOFF) {
            int g = blockIdx.x * 64 * KOFF + j;
            sNbr[j] = (g < N * KOFF) ? nbr[g] : N;
        }
    }
    __syncthreads();                                         // B1

    int nb[KOFF];
#pragma unroll
    for (int k = 0; k < KOFF; ++k) nb[k] = sNbr[rt * KOFF + k];

    // ---- pin all 18 gathers (72 regs), deep in flight ----
    bf16x8 ga[KOFF][2];
#pragma unroll
    for (int k = 0; k < KOFF; ++k) {
        const bf16x8* pg = reinterpret_cast<const bf16x8*>(out1 + (size_t)nb[k] * C_MID + quad * 8);
        ga[k][0] = pg[0];
        ga[k][1] = pg[4];
    }
    __builtin_amdgcn_sched_barrier(0);

    f32x4 acc2[4] = {};
    // ---- phase 0: k = 0..2 ----
#pragma unroll
    for (int k2 = 0; k2 < 3; ++k2) {
#pragma unroll
        for (int kk = 0; kk < 2; ++kk) {
#pragma unroll
            for (int ct = 0; ct < 4; ++ct) {
                bf16x8 fa = sW2c[((k2 * 2 + kk) * 4 + quad) * 64 + ct * 16 + l15];
                acc2[ct] = __builtin_amdgcn_mfma_f32_16x16x32_bf16(fa, ga[k2][kk], acc2[ct], 0, 0, 0);
            }
        }
    }
    __syncthreads();                                         // B2: phase0 reads done

    // ---- stage w2 phase1 (k=3..5) ----
#pragma unroll
    for (int it = 0; it < 6; ++it) {
        int s = it * 256 + t;
        int l = s & 15, ct = (s >> 4) & 3, q = (s >> 6) & 3, kk = (s >> 8) & 1, k2 = s >> 9;
        sW2c[s] = w2c[(3 + k2) * 512 + (ct * 16 + l) * 8 + kk * 4 + q];
    }
    __syncthreads();                                         // B3
#pragma unroll
    for (int k2 = 0; k2 < 3; ++k2) {
#pragma unroll
        for (int kk = 0; kk < 2; ++kk) {
#pragma unroll
            for (int ct = 0; ct < 4; ++ct) {
                bf16x8 fa = sW2c[((k2 * 2 + kk) * 4 + quad) * 64 + ct * 16 + l15];
                acc2[ct] = __builtin_amdgcn_mfma_f32_16x16x32_bf16(fa, ga[3 + k2][kk], acc2[ct], 0, 0, 0);
            }
        }
    }
    __syncthreads();                                         // B4: phase1 reads done

    // ---- stage w2 phase2 (k=6..8) ----
#pragma unroll
    for (int it = 0; it < 6; ++it) {
        int s = it * 256 + t;
        int l = s & 15, ct = (s >> 4) & 3, q = (s >> 6) & 3, kk = (s >> 8) & 1, k2 = s >> 9;
        sW2c[s] = w2c[(6 + k2) * 512 + (ct * 16 + l) * 8 + kk * 4 + q];
    }
    __syncthreads();                                         // B5
#pragma unroll
    for (int k2 = 0; k2 < 3; ++k2) {
#pragma unroll
        for (int kk = 0; kk < 2; ++kk) {
#pragma unroll
            for (int ct = 0; ct < 4; ++ct) {
                bf16x8 fa = sW2c[((k2 * 2 + kk) * 4 + quad) * 64 + ct * 16 + l15];
                acc2[ct] = __builtin_amdgcn_mfma_f32_16x16x32_bf16(fa, ga[6 + k2][kk], acc2[ct], 0, 0, 0);
            }
        }
    }

    // ---- bn2 + relu -> sMid (LDS transpose, pitch 72 -> 2-way alias, free) ----
#pragma unroll
    for (int ct = 0; ct < 4; ++ct) {
        float4v bb = *reinterpret_cast<const float4v*>(b2 + ct * 16 + quad * 4);
        union { unsigned short s[4]; short4v v; } o;
#pragma unroll
        for (int reg = 0; reg < 4; ++reg)
            o.s[reg] = f2bf(fmaxf(acc2[ct][reg] + bb[reg], 0.f));
        *reinterpret_cast<short4v*>(&sMid[rt * 72 + ct * 16 + quad * 4]) = o.v;
    }

    // ga dead — pin rf now (64 regs drain during the mid-RAW barrier)
    float4v rf[16];
#pragma unroll
    for (int c2 = 0; c2 < 16; ++c2)
        rf[c2] = *reinterpret_cast<const float4v*>(
            feat + (size_t)sitec * C_IN + c2 * 16 + quad * 4);
    __builtin_amdgcn_sched_barrier(0);
    __syncthreads();                                         // B6: mid RAW

    bf16x8 fb0 = *reinterpret_cast<const bf16x8*>(&sMid[rt * 72 + quad * 8]);
    bf16x8 fb1 = *reinterpret_cast<const bf16x8*>(&sMid[rt * 72 + 32 + quad * 8]);

    // ---- conv3: w3 fragments straight from L1/L2, chunked 4 x 4 out-ch ----
    const bf16x8* w3c = reinterpret_cast<const bf16x8*>(w3t);
#pragma unroll
    for (int c = 0; c < 4; ++c) {
        f32x4 acc3[4] = {};
#pragma unroll
        for (int c2l = 0; c2l < 4; ++c2l) {
            int c2 = c * 4 + c2l;
            bf16x8 fa0 = w3c[(c2 * 16 + l15) * 8 + quad];        // kk = 0
            acc3[c2l] = __builtin_amdgcn_mfma_f32_16x16x32_bf16(fa0, fb0, acc3[c2l], 0, 0, 0);
            bf16x8 fa1 = w3c[(c2 * 16 + l15) * 8 + 4 + quad];    // kk = 1
            acc3[c2l] = __builtin_amdgcn_mfma_f32_16x16x32_bf16(fa1, fb1, acc3[c2l], 0, 0, 0);
        }
        if (site < N) {
#pragma unroll
            for (int c2l = 0; c2l < 4; ++c2l) {
                int c2 = c * 4 + c2l;
                float4v bb = *reinterpret_cast<const float4v*>(b3 + c2 * 16 + quad * 4);
                float4v o;
#pragma unroll
                for (int reg = 0; reg < 4; ++reg)
                    o[reg] = fmaxf(acc3[c2l][reg] + bb[reg] + rf[c2][reg], 0.f);
                *reinterpret_cast<float4v*>(out + (size_t)site * C_IN + c2 * 16 + quad * 4) = o;
            }
        }
    }
}

extern "C" void kernel_launch(void* const* d_in, const int* in_sizes, int n_in,
                              void* d_out, int out_size, void* d_ws, size_t ws_size,
                              hipStream_t stream) {
    const float* feat = (const float*)d_in[0];
    const int*   nbr  = (const int*)d_in[1];
    const float* w1   = (const float*)d_in[2];
    const float* s1   = (const float*)d_in[3];
    const float* b1   = (const float*)d_in[4];
    const float* w2   = (const float*)d_in[5];
    const float* s2   = (const float*)d_in[6];
    const float* b2   = (const float*)d_in[7];
    const float* w3   = (const float*)d_in[8];
    const float* s3   = (const float*)d_in[9];
    const float* b3   = (const float*)d_in[10];
    float* out = (float*)d_out;
    int N = in_sizes[0] / C_IN;

    char* ws = (char*)d_ws;
    unsigned short* w1t  = (unsigned short*)(ws);                    // 32768 B
    unsigned short* w2t  = (unsigned short*)(ws + 32768);            // 73728 B
    unsigned short* w3t  = (unsigned short*)(ws + 32768 + 73728);    // 32768 B
    unsigned short* out1 = (unsigned short*)(ws + 139264);           // (N+1)*64*2 B

    prep_kernel<<<80, 256, 0, stream>>>(w1, s1, w2, s2, w3, s3, w1t, w2t, w3t,
                                        out1 + (size_t)N * C_MID);
    int nblk = (N + 63) / 64;
    conv1_kernel<<<nblk, 256, 0, stream>>>(feat, w1t, b1, out1, N);
    conv23_kernel<<<nblk, 256, 0, stream>>>(feat, nbr, out1, w2t, b2, w3t, b3, out, N);
}

// Round 6
// 272.928 us; speedup vs baseline: 1.0015x; 1.0015x over previous
//
#include <hip/hip_runtime.h>
#include <stdint.h>

#define C_IN 256
#define C_MID 64
#define KOFF 9

typedef __attribute__((ext_vector_type(8))) short bf16x8;   // 8 bf16 = 4 VGPRs
typedef __attribute__((ext_vector_type(4))) short short4v;  // 8 B packed bf16x4
typedef __attribute__((ext_vector_type(4))) float f32x4;    // MFMA C/D
typedef __attribute__((ext_vector_type(4))) float float4v;

// fp32 -> bf16 round-to-nearest-even
__device__ inline unsigned short f2bf(float f) {
    union { float f; unsigned u; } x; x.f = f;
    unsigned r = x.u + 0x7FFFu + ((x.u >> 16) & 1u);
    return (unsigned short)(r >> 16);
}

// ---------------------------------------------------------------------------
// prep (unchanged):
//   w1t[n][k] = bf16(w1[k][n] * s1[n])          [64][256]   16384 shorts
//   w2t[k][d][c] = bf16(w2[k][c][d] * s2[d])    [9][64][64] 36864 shorts
//   w3t[e][c] = bf16(w3[c][e] * s3[e])          [256][64]   16384 shorts
// ---------------------------------------------------------------------------
__global__ void prep_kernel(const float* __restrict__ w1, const float* __restrict__ s1,
                            const float* __restrict__ w2, const float* __restrict__ s2,
                            const float* __restrict__ w3, const float* __restrict__ s3,
                            unsigned short* __restrict__ w1t,
                            unsigned short* __restrict__ w2t,
                            unsigned short* __restrict__ w3t,
                            unsigned short* __restrict__ zrow) {
    int tid = blockIdx.x * blockDim.x + threadIdx.x;
    int stride = gridDim.x * blockDim.x;
    for (int i = tid; i < C_MID * C_IN; i += stride) {
        int n = i / C_IN, k = i % C_IN;
        w1t[i] = f2bf(w1[k * C_MID + n] * s1[n]);
    }
    for (int i = tid; i < KOFF * C_MID * C_MID; i += stride) {
        int k = i / (C_MID * C_MID);
        int r = i % (C_MID * C_MID);
        int d = r / C_MID, c = r % C_MID;
        w2t[i] = f2bf(w2[(k * C_MID + c) * C_MID + d] * s2[d]);
    }
    for (int i = tid; i < C_IN * C_MID; i += stride) {
        int e = i / C_MID, c = i % C_MID;
        w3t[i] = f2bf(w3[c * C_IN + e] * s3[e]);
    }
    for (int i = tid; i < C_MID; i += stride) zrow[i] = 0;
}

// ---------------------------------------------------------------------------
// conv1 v4 (R0 verbatim — part of the 260.7 µs baseline): role-swapped,
// LDS = sW1 only (32.8 KB -> 4 blocks/CU). fr loads split into two pinned
// groups of 8 float4 (peak ~95 regs <= 128 cap, no spill).
// ---------------------------------------------------------------------------
__global__ __launch_bounds__(256, 4) void conv1_kernel(
    const float* __restrict__ feat, const unsigned short* __restrict__ w1t,
    const float* __restrict__ b1, unsigned short* __restrict__ out1, int N)
{
    __shared__ __align__(16) unsigned short sW1[16384];      // 32768 B

    int t = threadIdx.x;
    int wave = t >> 6;
    int lane = t & 63;
    int l15 = lane & 15;
    int quad = lane >> 4;
    int site = blockIdx.x * 64 + wave * 16 + l15;
    int sitec = site < N ? site : (N - 1);

    const bf16x8* w1c = reinterpret_cast<const bf16x8*>(w1t);
    bf16x8* sW1c = reinterpret_cast<bf16x8*>(sW1);
#pragma unroll
    for (int it = 0; it < 8; ++it) {
        int s = it * 256 + t;
        int l = s & 15, ct = (s >> 4) & 3, q = (s >> 6) & 3, kk = s >> 8;
        sW1c[s] = w1c[(ct * 16 + l) * 32 + kk * 4 + q];
    }

    // ---- pin group 0: kk = 0..3 (8 float4 = 32 regs) ----
    float4v fr0[8];
#pragma unroll
    for (int kk = 0; kk < 4; ++kk) {
        const float4v* p = reinterpret_cast<const float4v*>(
            feat + (size_t)sitec * C_IN + kk * 32 + quad * 8);
        fr0[kk * 2] = p[0];
        fr0[kk * 2 + 1] = p[1];
    }
    __builtin_amdgcn_sched_barrier(0);
    __syncthreads();

    // ---- pin group 1: kk = 4..7 (in flight during group-0 compute) ----
    float4v fr1[8];
#pragma unroll
    for (int kk = 0; kk < 4; ++kk) {
        const float4v* p = reinterpret_cast<const float4v*>(
            feat + (size_t)sitec * C_IN + (kk + 4) * 32 + quad * 8);
        fr1[kk * 2] = p[0];
        fr1[kk * 2 + 1] = p[1];
    }
    __builtin_amdgcn_sched_barrier(0);

    f32x4 acc[4] = {};
#pragma unroll
    for (int kk = 0; kk < 4; ++kk) {
        union { unsigned short s[8]; bf16x8 v; } ua;
#pragma unroll
        for (int j = 0; j < 4; ++j) {
            ua.s[j] = f2bf(fr0[kk * 2][j]);
            ua.s[4 + j] = f2bf(fr0[kk * 2 + 1][j]);
        }
#pragma unroll
        for (int ct = 0; ct < 4; ++ct) {
            bf16x8 fa = sW1c[((kk * 4 + quad) * 4 + ct) * 16 + l15];
            acc[ct] = __builtin_amdgcn_mfma_f32_16x16x32_bf16(fa, ua.v, acc[ct], 0, 0, 0);
        }
    }
#pragma unroll
    for (int kk = 0; kk < 4; ++kk) {
        union { unsigned short s[8]; bf16x8 v; } ua;
#pragma unroll
        for (int j = 0; j < 4; ++j) {
            ua.s[j] = f2bf(fr1[kk * 2][j]);
            ua.s[4 + j] = f2bf(fr1[kk * 2 + 1][j]);
        }
#pragma unroll
        for (int ct = 0; ct < 4; ++ct) {
            bf16x8 fa = sW1c[(((kk + 4) * 4 + quad) * 4 + ct) * 16 + l15];
            acc[ct] = __builtin_amdgcn_mfma_f32_16x16x32_bf16(fa, ua.v, acc[ct], 0, 0, 0);
        }
    }
    if (site < N) {
#pragma unroll
        for (int ct = 0; ct < 4; ++ct) {
            float4v bb = *reinterpret_cast<const float4v*>(b1 + ct * 16 + quad * 4);
            union { unsigned short s[4]; short4v v; } o;
#pragma unroll
            for (int reg = 0; reg < 4; ++reg)
                o.s[reg] = f2bf(fmaxf(acc[ct][reg] + bb[reg], 0.f));
            *reinterpret_cast<short4v*>(out1 + (size_t)site * C_MID + ct * 16 + quad * 4) = o.v;
        }
    }
}

// ---------------------------------------------------------------------------
// conv23 v9: R0 skeleton (identical through the rf pin — the VGPR-84 build
// that keeps all 18 gathers in flight), with the tail de-serialized:
//   - w3 read DIRECTLY from global/L1 (32 KB, L1-resident; numerics proven
//     in R4/R5) -> no w3 overlay into the w2 staging region -> the cross-
//     wave hazard that required B4/B5 is gone.
//   - mid transpose is INTRA-WAVE (acc2 for site rt lives in lanes {l15,
//     quad 0..3} of the same wave; fb reads the same wave's 16 rows), so
//     program order + lgkmcnt suffices — no barrier.
// Barriers: 5 -> 3. mid lives at shorts 16384..20991 (w2-p1 territory, dead
// since B2; p2 reads touch only shorts 0..16383). LDS = 41984 + 2304 B
// -> 3 blocks/CU, same as R0.
// ---------------------------------------------------------------------------
__global__ __launch_bounds__(256, 2) void conv23_kernel(
    const float* __restrict__ feat, const int* __restrict__ nbr,
    const unsigned short* __restrict__ out1, const unsigned short* __restrict__ w2t,
    const float* __restrict__ b2, const unsigned short* __restrict__ w3t,
    const float* __restrict__ b3, float* __restrict__ out, int N)
{
    __shared__ __align__(16) unsigned short sWB[20992];      // 41984 B
    __shared__ int sNbr[64 * KOFF];                          // 2304 B

    int t = threadIdx.x;
    int wave = t >> 6;
    int lane = t & 63;
    int l15 = lane & 15;
    int quad = lane >> 4;
    int rt = wave * 16 + l15;
    int site = blockIdx.x * 64 + rt;
    int sitec = site < N ? site : (N - 1);

    bf16x8* sWBc = reinterpret_cast<bf16x8*>(sWB);
    const bf16x8* w2c = reinterpret_cast<const bf16x8*>(w2t);

    // ---- A1 stage: w2 k=0..4, 2560 chunks / 256 thr = 10 each (R0) ----
#pragma unroll
    for (int it = 0; it < 10; ++it) {
        int s = it * 256 + t;
        int l = s & 15, ct = (s >> 4) & 3, q = (s >> 6) & 3, kk = (s >> 8) & 1, k = s >> 9;
        sWBc[s] = w2c[k * 512 + (ct * 16 + l) * 8 + kk * 4 + q];
    }
#pragma unroll
    for (int i = 0; i < 3; ++i) {
        int j = i * 256 + t;
        if (j < 64 * KOFF) {
            int g = blockIdx.x * 64 * KOFF + j;
            sNbr[j] = (g < N * KOFF) ? nbr[g] : N;
        }
    }
    __syncthreads();                                         // B1

    int nb[KOFF];
#pragma unroll
    for (int k = 0; k < KOFF; ++k) nb[k] = sNbr[rt * KOFF + k];

    // ---- pin 18 gathers (R0-exact) ----
    bf16x8 ga[KOFF][2];
#pragma unroll
    for (int k = 0; k < KOFF; ++k) {
        const bf16x8* pg = reinterpret_cast<const bf16x8*>(out1 + (size_t)nb[k] * C_MID + quad * 8);
        ga[k][0] = pg[0];
        ga[k][1] = pg[4];
    }
    __builtin_amdgcn_sched_barrier(0);

    f32x4 acc2[4] = {};
#pragma unroll
    for (int k = 0; k < 5; ++k) {
#pragma unroll
        for (int kk = 0; kk < 2; ++kk) {
#pragma unroll
            for (int ct = 0; ct < 4; ++ct) {
                bf16x8 fa = sWBc[((k * 2 + kk) * 4 + quad) * 64 + ct * 16 + l15];
                acc2[ct] = __builtin_amdgcn_mfma_f32_16x16x32_bf16(fa, ga[k][kk], acc2[ct], 0, 0, 0);
            }
        }
    }
    __syncthreads();                                         // B2: w2 part1 read done

    // ---- A2 stage: w2 k=5..8 overlaid into chunks 0..2047 (R0) ----
#pragma unroll
    for (int it = 0; it < 8; ++it) {
        int s = it * 256 + t;
        int l = s & 15, ct = (s >> 4) & 3, q = (s >> 6) & 3, kk = (s >> 8) & 1, k2 = s >> 9;
        sWBc[s] = w2c[(5 + k2) * 512 + (ct * 16 + l) * 8 + kk * 4 + q];
    }
    __syncthreads();                                         // B3
#pragma unroll
    for (int k = 5; k < KOFF; ++k) {
        int kloc = k - 5;
#pragma unroll
        for (int kk = 0; kk < 2; ++kk) {
#pragma unroll
            for (int ct = 0; ct < 4; ++ct) {
                bf16x8 fa = sWBc[((kloc * 2 + kk) * 4 + quad) * 64 + ct * 16 + l15];
                acc2[ct] = __builtin_amdgcn_mfma_f32_16x16x32_bf16(fa, ga[k][kk], acc2[ct], 0, 0, 0);
            }
        }
    }
    // ga dead — pin rf now (R0-exact position; drains under the tail)
    float4v rf[16];
#pragma unroll
    for (int c2 = 0; c2 < 16; ++c2)
        rf[c2] = *reinterpret_cast<const float4v*>(
            feat + (size_t)sitec * C_IN + c2 * 16 + quad * 4);
    __builtin_amdgcn_sched_barrier(0);

    // ---- mid (pitch 72) at shorts 16384..20991 — NO barrier needed:
    // region dead since B2 (p1), p2 reads stay in shorts 0..16383, and the
    // RAW below is intra-wave (own 16 rows), ordered by lgkmcnt. ----
    unsigned short* mid = &sWB[16384];
#pragma unroll
    for (int ct = 0; ct < 4; ++ct) {
        float4v bb = *reinterpret_cast<const float4v*>(b2 + ct * 16 + quad * 4);
        union { unsigned short s[4]; short4v v; } o;
#pragma unroll
        for (int reg = 0; reg < 4; ++reg)
            o.s[reg] = f2bf(fmaxf(acc2[ct][reg] + bb[reg], 0.f));
        *reinterpret_cast<short4v*>(&mid[rt * 72 + ct * 16 + quad * 4]) = o.v;
    }

    // ---- conv3: fb from own-wave mid slice; w3 straight from L1/L2 ----
    const bf16x8* w3c = reinterpret_cast<const bf16x8*>(w3t);
    f32x4 acc3[16] = {};
#pragma unroll
    for (int kk = 0; kk < 2; ++kk) {
        bf16x8 fb = *reinterpret_cast<const bf16x8*>(
            &mid[rt * 72 + kk * 32 + quad * 8]);
#pragma unroll
        for (int c2 = 0; c2 < 16; ++c2) {
            bf16x8 fa = w3c[(c2 * 16 + l15) * 8 + kk * 4 + quad];
            acc3[c2] = __builtin_amdgcn_mfma_f32_16x16x32_bf16(fa, fb, acc3[c2], 0, 0, 0);
        }
    }
    if (site < N) {
#pragma unroll
        for (int c2 = 0; c2 < 16; ++c2) {
            float4v bb = *reinterpret_cast<const float4v*>(b3 + c2 * 16 + quad * 4);
            float4v o;
#pragma unroll
            for (int reg = 0; reg < 4; ++reg)
                o[reg] = fmaxf(acc3[c2][reg] + bb[reg] + rf[c2][reg], 0.f);
            *reinterpret_cast<float4v*>(out + (size_t)site * C_IN + c2 * 16 + quad * 4) = o;
        }
    }
}

extern "C" void kernel_launch(void* const* d_in, const int* in_sizes, int n_in,
                              void* d_out, int out_size, void* d_ws, size_t ws_size,
                              hipStream_t stream) {
    const float* feat = (const float*)d_in[0];
    const int*   nbr  = (const int*)d_in[1];
    const float* w1   = (const float*)d_in[2];
    const float* s1   = (const float*)d_in[3];
    const float* b1   = (const float*)d_in[4];
    const float* w2   = (const float*)d_in[5];
    const float* s2   = (const float*)d_in[6];
    const float* b2   = (const float*)d_in[7];
    const float* w3   = (const float*)d_in[8];
    const float* s3   = (const float*)d_in[9];
    const float* b3   = (const float*)d_in[10];
    float* out = (float*)d_out;
    int N = in_sizes[0] / C_IN;

    char* ws = (char*)d_ws;
    unsigned short* w1t  = (unsigned short*)(ws);                    // 32768 B
    unsigned short* w2t  = (unsigned short*)(ws + 32768);            // 73728 B
    unsigned short* w3t  = (unsigned short*)(ws + 32768 + 73728);    // 32768 B
    unsigned short* out1 = (unsigned short*)(ws + 139264);           // (N+1)*64*2 B

    prep_kernel<<<80, 256, 0, stream>>>(w1, s1, w2, s2, w3, s3, w1t, w2t, w3t,
                                        out1 + (size_t)N * C_MID);
    int nblk = (N + 63) / 64;
    conv1_kernel<<<nblk, 256, 0, stream>>>(feat, w1t, b1, out1, N);
    conv23_kernel<<<nblk, 256, 0, stream>>>(feat, nbr, out1, w2t, b2, w3t, b3, out, N);
}

// Round 7
// 266.326 us; speedup vs baseline: 1.0263x; 1.0248x over previous
//
#include <hip/hip_runtime.h>
#include <stdint.h>

#define C_IN 256
#define C_MID 64
#define KOFF 9

typedef __attribute__((ext_vector_type(8))) short bf16x8;   // 8 bf16 = 4 VGPRs
typedef __attribute__((ext_vector_type(4))) short short4v;  // 8 B packed bf16x4
typedef __attribute__((ext_vector_type(4))) float f32x4;    // MFMA C/D
typedef __attribute__((ext_vector_type(4))) float float4v;

// fp32 -> bf16 round-to-nearest-even
__device__ inline unsigned short f2bf(float f) {
    union { float f; unsigned u; } x; x.f = f;
    unsigned r = x.u + 0x7FFFu + ((x.u >> 16) & 1u);
    return (unsigned short)(r >> 16);
}

// ---------------------------------------------------------------------------
// prep (unchanged):
//   w1t[n][k] = bf16(w1[k][n] * s1[n])          [64][256]   16384 shorts
//   w2t[k][d][c] = bf16(w2[k][c][d] * s2[d])    [9][64][64] 36864 shorts
//   w3t[e][c] = bf16(w3[c][e] * s3[e])          [256][64]   16384 shorts
// ---------------------------------------------------------------------------
__global__ void prep_kernel(const float* __restrict__ w1, const float* __restrict__ s1,
                            const float* __restrict__ w2, const float* __restrict__ s2,
                            const float* __restrict__ w3, const float* __restrict__ s3,
                            unsigned short* __restrict__ w1t,
                            unsigned short* __restrict__ w2t,
                            unsigned short* __restrict__ w3t,
                            unsigned short* __restrict__ zrow) {
    int tid = blockIdx.x * blockDim.x + threadIdx.x;
    int stride = gridDim.x * blockDim.x;
    for (int i = tid; i < C_MID * C_IN; i += stride) {
        int n = i / C_IN, k = i % C_IN;
        w1t[i] = f2bf(w1[k * C_MID + n] * s1[n]);
    }
    for (int i = tid; i < KOFF * C_MID * C_MID; i += stride) {
        int k = i / (C_MID * C_MID);
        int r = i % (C_MID * C_MID);
        int d = r / C_MID, c = r % C_MID;
        w2t[i] = f2bf(w2[(k * C_MID + c) * C_MID + d] * s2[d]);
    }
    for (int i = tid; i < C_IN * C_MID; i += stride) {
        int e = i / C_MID, c = i % C_MID;
        w3t[i] = f2bf(w3[c * C_IN + e] * s3[e]);
    }
    for (int i = tid; i < C_MID; i += stride) zrow[i] = 0;
}

// ---------------------------------------------------------------------------
// conv1 v4 (R0 verbatim — part of the 260.7 µs baseline): role-swapped,
// LDS = sW1 only (32.8 KB -> 4 blocks/CU). fr loads split into two pinned
// groups of 8 float4 (peak ~95 regs <= 128 cap, no spill).
// ---------------------------------------------------------------------------
__global__ __launch_bounds__(256, 4) void conv1_kernel(
    const float* __restrict__ feat, const unsigned short* __restrict__ w1t,
    const float* __restrict__ b1, unsigned short* __restrict__ out1, int N)
{
    __shared__ __align__(16) unsigned short sW1[16384];      // 32768 B

    int t = threadIdx.x;
    int wave = t >> 6;
    int lane = t & 63;
    int l15 = lane & 15;
    int quad = lane >> 4;
    int site = blockIdx.x * 64 + wave * 16 + l15;
    int sitec = site < N ? site : (N - 1);

    const bf16x8* w1c = reinterpret_cast<const bf16x8*>(w1t);
    bf16x8* sW1c = reinterpret_cast<bf16x8*>(sW1);
#pragma unroll
    for (int it = 0; it < 8; ++it) {
        int s = it * 256 + t;
        int l = s & 15, ct = (s >> 4) & 3, q = (s >> 6) & 3, kk = s >> 8;
        sW1c[s] = w1c[(ct * 16 + l) * 32 + kk * 4 + q];
    }

    // ---- pin group 0: kk = 0..3 (8 float4 = 32 regs) ----
    float4v fr0[8];
#pragma unroll
    for (int kk = 0; kk < 4; ++kk) {
        const float4v* p = reinterpret_cast<const float4v*>(
            feat + (size_t)sitec * C_IN + kk * 32 + quad * 8);
        fr0[kk * 2] = p[0];
        fr0[kk * 2 + 1] = p[1];
    }
    __builtin_amdgcn_sched_barrier(0);
    __syncthreads();

    // ---- pin group 1: kk = 4..7 (in flight during group-0 compute) ----
    float4v fr1[8];
#pragma unroll
    for (int kk = 0; kk < 4; ++kk) {
        const float4v* p = reinterpret_cast<const float4v*>(
            feat + (size_t)sitec * C_IN + (kk + 4) * 32 + quad * 8);
        fr1[kk * 2] = p[0];
        fr1[kk * 2 + 1] = p[1];
    }
    __builtin_amdgcn_sched_barrier(0);

    f32x4 acc[4] = {};
#pragma unroll
    for (int kk = 0; kk < 4; ++kk) {
        union { unsigned short s[8]; bf16x8 v; } ua;
#pragma unroll
        for (int j = 0; j < 4; ++j) {
            ua.s[j] = f2bf(fr0[kk * 2][j]);
            ua.s[4 + j] = f2bf(fr0[kk * 2 + 1][j]);
        }
#pragma unroll
        for (int ct = 0; ct < 4; ++ct) {
            bf16x8 fa = sW1c[((kk * 4 + quad) * 4 + ct) * 16 + l15];
            acc[ct] = __builtin_amdgcn_mfma_f32_16x16x32_bf16(fa, ua.v, acc[ct], 0, 0, 0);
        }
    }
#pragma unroll
    for (int kk = 0; kk < 4; ++kk) {
        union { unsigned short s[8]; bf16x8 v; } ua;
#pragma unroll
        for (int j = 0; j < 4; ++j) {
            ua.s[j] = f2bf(fr1[kk * 2][j]);
            ua.s[4 + j] = f2bf(fr1[kk * 2 + 1][j]);
        }
#pragma unroll
        for (int ct = 0; ct < 4; ++ct) {
            bf16x8 fa = sW1c[(((kk + 4) * 4 + quad) * 4 + ct) * 16 + l15];
            acc[ct] = __builtin_amdgcn_mfma_f32_16x16x32_bf16(fa, ua.v, acc[ct], 0, 0, 0);
        }
    }
    if (site < N) {
#pragma unroll
        for (int ct = 0; ct < 4; ++ct) {
            float4v bb = *reinterpret_cast<const float4v*>(b1 + ct * 16 + quad * 4);
            union { unsigned short s[4]; short4v v; } o;
#pragma unroll
            for (int reg = 0; reg < 4; ++reg)
                o.s[reg] = f2bf(fmaxf(acc[ct][reg] + bb[reg], 0.f));
            *reinterpret_cast<short4v*>(out1 + (size_t)site * C_MID + ct * 16 + quad * 4) = o.v;
        }
    }
}

// ---------------------------------------------------------------------------
// conv23 v10: R0 structure EXACTLY (same phases, overlays, barriers, pin
// placement — the empirically-proven shape; v5/v8/v9 showed weights must be
// LDS-staged and the tail overlay scheme must stay), scaled to 512 threads /
// 8 waves / 128 sites per block. Per-wave dataflow byte-identical (each wave
// owns 16 sites via rt = wave*16+l15). Halves staging instructions, weight
// L2 traffic, and barriers PER SITE; 2 blocks/CU x 8 waves = 16 waves/CU
// (vs R0's 12). Buffer layout (shorts):
//   A1: w2 k0-4 chunks 0..2559 (shorts 0..20479)
//   A2: w2 k5-8 chunks 0..2047 (shorts 0..16383)
//   B : w3 chunks 0..2047 (shorts 0..16383) | mid pitch 72 at 16384..25599
// LDS = 51200 (sWB) + 4608 (nbr) = 55808 B.
// ---------------------------------------------------------------------------
__global__ __launch_bounds__(512, 2) void conv23_kernel(
    const float* __restrict__ feat, const int* __restrict__ nbr,
    const unsigned short* __restrict__ out1, const unsigned short* __restrict__ w2t,
    const float* __restrict__ b2, const unsigned short* __restrict__ w3t,
    const float* __restrict__ b3, float* __restrict__ out, int N)
{
    __shared__ __align__(16) unsigned short sWB[25600];      // 51200 B
    __shared__ int sNbr[128 * KOFF];                         // 4608 B

    int t = threadIdx.x;
    int wave = t >> 6;
    int lane = t & 63;
    int l15 = lane & 15;
    int quad = lane >> 4;
    int rt = wave * 16 + l15;                                // 0..127
    int site = blockIdx.x * 128 + rt;
    int sitec = site < N ? site : (N - 1);

    bf16x8* sWBc = reinterpret_cast<bf16x8*>(sWB);
    const bf16x8* w2c = reinterpret_cast<const bf16x8*>(w2t);

    // ---- A1 stage: w2 k=0..4, 2560 chunks / 512 thr = 5 each ----
#pragma unroll
    for (int it = 0; it < 5; ++it) {
        int s = it * 512 + t;
        int l = s & 15, ct = (s >> 4) & 3, q = (s >> 6) & 3, kk = (s >> 8) & 1, k = s >> 9;
        sWBc[s] = w2c[k * 512 + (ct * 16 + l) * 8 + kk * 4 + q];
    }
#pragma unroll
    for (int i = 0; i < 3; ++i) {
        int j = i * 512 + t;
        if (j < 128 * KOFF) {
            int g = blockIdx.x * 128 * KOFF + j;
            sNbr[j] = (g < N * KOFF) ? nbr[g] : N;
        }
    }
    __syncthreads();                                         // B1

    int nb[KOFF];
#pragma unroll
    for (int k = 0; k < KOFF; ++k) nb[k] = sNbr[rt * KOFF + k];

    // ---- pin 18 gathers (R0-exact per thread) ----
    bf16x8 ga[KOFF][2];
#pragma unroll
    for (int k = 0; k < KOFF; ++k) {
        const bf16x8* pg = reinterpret_cast<const bf16x8*>(out1 + (size_t)nb[k] * C_MID + quad * 8);
        ga[k][0] = pg[0];
        ga[k][1] = pg[4];
    }
    __builtin_amdgcn_sched_barrier(0);

    f32x4 acc2[4] = {};
#pragma unroll
    for (int k = 0; k < 5; ++k) {
#pragma unroll
        for (int kk = 0; kk < 2; ++kk) {
#pragma unroll
            for (int ct = 0; ct < 4; ++ct) {
                bf16x8 fa = sWBc[((k * 2 + kk) * 4 + quad) * 64 + ct * 16 + l15];
                acc2[ct] = __builtin_amdgcn_mfma_f32_16x16x32_bf16(fa, ga[k][kk], acc2[ct], 0, 0, 0);
            }
        }
    }
    __syncthreads();                                         // B2: w2 part1 read done

    // ---- A2 stage: w2 k=5..8 overlaid into chunks 0..2047 ----
#pragma unroll
    for (int it = 0; it < 4; ++it) {
        int s = it * 512 + t;
        int l = s & 15, ct = (s >> 4) & 3, q = (s >> 6) & 3, kk = (s >> 8) & 1, k2 = s >> 9;
        sWBc[s] = w2c[(5 + k2) * 512 + (ct * 16 + l) * 8 + kk * 4 + q];
    }
    __syncthreads();                                         // B3
#pragma unroll
    for (int k = 5; k < KOFF; ++k) {
        int kloc = k - 5;
#pragma unroll
        for (int kk = 0; kk < 2; ++kk) {
#pragma unroll
            for (int ct = 0; ct < 4; ++ct) {
                bf16x8 fa = sWBc[((kloc * 2 + kk) * 4 + quad) * 64 + ct * 16 + l15];
                acc2[ct] = __builtin_amdgcn_mfma_f32_16x16x32_bf16(fa, ga[k][kk], acc2[ct], 0, 0, 0);
            }
        }
    }
    // ga dead — pin rf now (drains during staging + barrier)
    float4v rf[16];
#pragma unroll
    for (int c2 = 0; c2 < 16; ++c2)
        rf[c2] = *reinterpret_cast<const float4v*>(
            feat + (size_t)sitec * C_IN + c2 * 16 + quad * 4);
    __builtin_amdgcn_sched_barrier(0);
    __syncthreads();                                         // B4: w2 part2 read done

    // ---- phase B: mid (pitch 72) at shorts 16384..25599; w3 chunks 0..2047 ----
    unsigned short* mid = &sWB[16384];
#pragma unroll
    for (int ct = 0; ct < 4; ++ct) {
        float4v bb = *reinterpret_cast<const float4v*>(b2 + ct * 16 + quad * 4);
        union { unsigned short s[4]; short4v v; } o;
#pragma unroll
        for (int reg = 0; reg < 4; ++reg)
            o.s[reg] = f2bf(fmaxf(acc2[ct][reg] + bb[reg], 0.f));
        *reinterpret_cast<short4v*>(&mid[rt * 72 + ct * 16 + quad * 4]) = o.v;
    }
    const bf16x8* w3c = reinterpret_cast<const bf16x8*>(w3t);
#pragma unroll
    for (int it = 0; it < 4; ++it) {
        int s = it * 512 + t;
        int l = s & 15, c2 = (s >> 4) & 15, q = (s >> 8) & 3, kk = (s >> 10) & 1;
        sWBc[s] = w3c[(c2 * 16 + l) * 8 + kk * 4 + q];
    }
    __syncthreads();                                         // B5 (w3 + mid visible)

    f32x4 acc3[16] = {};
#pragma unroll
    for (int kk = 0; kk < 2; ++kk) {
        bf16x8 fb = *reinterpret_cast<const bf16x8*>(
            &mid[rt * 72 + kk * 32 + quad * 8]);
#pragma unroll
        for (int c2 = 0; c2 < 16; ++c2) {
            bf16x8 fa = sWBc[((kk * 4 + quad) * 16 + c2) * 16 + l15];
            acc3[c2] = __builtin_amdgcn_mfma_f32_16x16x32_bf16(fa, fb, acc3[c2], 0, 0, 0);
        }
    }
    if (site < N) {
#pragma unroll
        for (int c2 = 0; c2 < 16; ++c2) {
            float4v bb = *reinterpret_cast<const float4v*>(b3 + c2 * 16 + quad * 4);
            float4v o;
#pragma unroll
            for (int reg = 0; reg < 4; ++reg)
                o[reg] = fmaxf(acc3[c2][reg] + bb[reg] + rf[c2][reg], 0.f);
            *reinterpret_cast<float4v*>(out + (size_t)site * C_IN + c2 * 16 + quad * 4) = o;
        }
    }
}

extern "C" void kernel_launch(void* const* d_in, const int* in_sizes, int n_in,
                              void* d_out, int out_size, void* d_ws, size_t ws_size,
                              hipStream_t stream) {
    const float* feat = (const float*)d_in[0];
    const int*   nbr  = (const int*)d_in[1];
    const float* w1   = (const float*)d_in[2];
    const float* s1   = (const float*)d_in[3];
    const float* b1   = (const float*)d_in[4];
    const float* w2   = (const float*)d_in[5];
    const float* s2   = (const float*)d_in[6];
    const float* b2   = (const float*)d_in[7];
    const float* w3   = (const float*)d_in[8];
    const float* s3   = (const float*)d_in[9];
    const float* b3   = (const float*)d_in[10];
    float* out = (float*)d_out;
    int N = in_sizes[0] / C_IN;

    char* ws = (char*)d_ws;
    unsigned short* w1t  = (unsigned short*)(ws);                    // 32768 B
    unsigned short* w2t  = (unsigned short*)(ws + 32768);            // 73728 B
    unsigned short* w3t  = (unsigned short*)(ws + 32768 + 73728);    // 32768 B
    unsigned short* out1 = (unsigned short*)(ws + 139264);           // (N+1)*64*2 B

    prep_kernel<<<80, 256, 0, stream>>>(w1, s1, w2, s2, w3, s3, w1t, w2t, w3t,
                                        out1 + (size_t)N * C_MID);
    int nblk1 = (N + 63) / 64;
    conv1_kernel<<<nblk1, 256, 0, stream>>>(feat, w1t, b1, out1, N);
    int nblk2 = (N + 127) / 128;
    conv23_kernel<<<nblk2, 512, 0, stream>>>(feat, nbr, out1, w2t, b2, w3t, b3, out, N);
}

// Round 8
// 261.545 us; speedup vs baseline: 1.0451x; 1.0183x over previous
//
#include <hip/hip_runtime.h>
#include <stdint.h>

#define C_IN 256
#define C_MID 64
#define KOFF 9

typedef __attribute__((ext_vector_type(8))) short bf16x8;   // 8 bf16 = 4 VGPRs
typedef __attribute__((ext_vector_type(4))) short short4v;  // 8 B packed bf16x4
typedef __attribute__((ext_vector_type(4))) float f32x4;    // MFMA C/D
typedef __attribute__((ext_vector_type(4))) float float4v;

// fp32 -> bf16 round-to-nearest-even
__device__ inline unsigned short f2bf(float f) {
    union { float f; unsigned u; } x; x.f = f;
    unsigned r = x.u + 0x7FFFu + ((x.u >> 16) & 1u);
    return (unsigned short)(r >> 16);
}

// ---------------------------------------------------------------------------
// prep (unchanged):
//   w1t[n][k] = bf16(w1[k][n] * s1[n])          [64][256]   16384 shorts
//   w2t[k][d][c] = bf16(w2[k][c][d] * s2[d])    [9][64][64] 36864 shorts
//   w3t[e][c] = bf16(w3[c][e] * s3[e])          [256][64]   16384 shorts
// ---------------------------------------------------------------------------
__global__ void prep_kernel(const float* __restrict__ w1, const float* __restrict__ s1,
                            const float* __restrict__ w2, const float* __restrict__ s2,
                            const float* __restrict__ w3, const float* __restrict__ s3,
                            unsigned short* __restrict__ w1t,
                            unsigned short* __restrict__ w2t,
                            unsigned short* __restrict__ w3t,
                            unsigned short* __restrict__ zrow) {
    int tid = blockIdx.x * blockDim.x + threadIdx.x;
    int stride = gridDim.x * blockDim.x;
    for (int i = tid; i < C_MID * C_IN; i += stride) {
        int n = i / C_IN, k = i % C_IN;
        w1t[i] = f2bf(w1[k * C_MID + n] * s1[n]);
    }
    for (int i = tid; i < KOFF * C_MID * C_MID; i += stride) {
        int k = i / (C_MID * C_MID);
        int r = i % (C_MID * C_MID);
        int d = r / C_MID, c = r % C_MID;
        w2t[i] = f2bf(w2[(k * C_MID + c) * C_MID + d] * s2[d]);
    }
    for (int i = tid; i < C_IN * C_MID; i += stride) {
        int e = i / C_MID, c = i % C_MID;
        w3t[i] = f2bf(w3[c * C_IN + e] * s3[e]);
    }
    for (int i = tid; i < C_MID; i += stride) zrow[i] = 0;
}

// ---------------------------------------------------------------------------
// conv1 v11: same per-thread dataflow as the R0-proven v4, scaled to 512
// threads / 8 waves / 128 sites per block. Halves w1-staging instructions,
// staging L2 traffic, and barrier count PER SITE. (512,2): VGPR cap 256 —
// the fr pin groups (2 x 32 regs) cannot be demoted (peak live ~95).
// LDS unchanged at 32768 B.
// ---------------------------------------------------------------------------
__global__ __launch_bounds__(512, 2) void conv1_kernel(
    const float* __restrict__ feat, const unsigned short* __restrict__ w1t,
    const float* __restrict__ b1, unsigned short* __restrict__ out1, int N)
{
    __shared__ __align__(16) unsigned short sW1[16384];      // 32768 B

    int t = threadIdx.x;
    int wave = t >> 6;
    int lane = t & 63;
    int l15 = lane & 15;
    int quad = lane >> 4;
    int site = blockIdx.x * 128 + wave * 16 + l15;
    int sitec = site < N ? site : (N - 1);

    const bf16x8* w1c = reinterpret_cast<const bf16x8*>(w1t);
    bf16x8* sW1c = reinterpret_cast<bf16x8*>(sW1);
    // 2048 chunks / 512 threads = 4 per thread (was 8)
#pragma unroll
    for (int it = 0; it < 4; ++it) {
        int s = it * 512 + t;
        int l = s & 15, ct = (s >> 4) & 3, q = (s >> 6) & 3, kk = s >> 8;
        sW1c[s] = w1c[(ct * 16 + l) * 32 + kk * 4 + q];
    }

    // ---- pin group 0: kk = 0..3 (8 float4 = 32 regs) ----
    float4v fr0[8];
#pragma unroll
    for (int kk = 0; kk < 4; ++kk) {
        const float4v* p = reinterpret_cast<const float4v*>(
            feat + (size_t)sitec * C_IN + kk * 32 + quad * 8);
        fr0[kk * 2] = p[0];
        fr0[kk * 2 + 1] = p[1];
    }
    __builtin_amdgcn_sched_barrier(0);
    __syncthreads();

    // ---- pin group 1: kk = 4..7 (in flight during group-0 compute) ----
    float4v fr1[8];
#pragma unroll
    for (int kk = 0; kk < 4; ++kk) {
        const float4v* p = reinterpret_cast<const float4v*>(
            feat + (size_t)sitec * C_IN + (kk + 4) * 32 + quad * 8);
        fr1[kk * 2] = p[0];
        fr1[kk * 2 + 1] = p[1];
    }
    __builtin_amdgcn_sched_barrier(0);

    f32x4 acc[4] = {};
#pragma unroll
    for (int kk = 0; kk < 4; ++kk) {
        union { unsigned short s[8]; bf16x8 v; } ua;
#pragma unroll
        for (int j = 0; j < 4; ++j) {
            ua.s[j] = f2bf(fr0[kk * 2][j]);
            ua.s[4 + j] = f2bf(fr0[kk * 2 + 1][j]);
        }
#pragma unroll
        for (int ct = 0; ct < 4; ++ct) {
            bf16x8 fa = sW1c[((kk * 4 + quad) * 4 + ct) * 16 + l15];
            acc[ct] = __builtin_amdgcn_mfma_f32_16x16x32_bf16(fa, ua.v, acc[ct], 0, 0, 0);
        }
    }
#pragma unroll
    for (int kk = 0; kk < 4; ++kk) {
        union { unsigned short s[8]; bf16x8 v; } ua;
#pragma unroll
        for (int j = 0; j < 4; ++j) {
            ua.s[j] = f2bf(fr1[kk * 2][j]);
            ua.s[4 + j] = f2bf(fr1[kk * 2 + 1][j]);
        }
#pragma unroll
        for (int ct = 0; ct < 4; ++ct) {
            bf16x8 fa = sW1c[(((kk + 4) * 4 + quad) * 4 + ct) * 16 + l15];
            acc[ct] = __builtin_amdgcn_mfma_f32_16x16x32_bf16(fa, ua.v, acc[ct], 0, 0, 0);
        }
    }
    if (site < N) {
#pragma unroll
        for (int ct = 0; ct < 4; ++ct) {
            float4v bb = *reinterpret_cast<const float4v*>(b1 + ct * 16 + quad * 4);
            union { unsigned short s[4]; short4v v; } o;
#pragma unroll
            for (int reg = 0; reg < 4; ++reg)
                o.s[reg] = f2bf(fmaxf(acc[ct][reg] + bb[reg], 0.f));
            *reinterpret_cast<short4v*>(out1 + (size_t)site * C_MID + ct * 16 + quad * 4) = o.v;
        }
    }
}

// ---------------------------------------------------------------------------
// conv23 — R0 BYTE-EXACT (74.5 µs proven; VGPR-84 build). v5/v8/v9/v10 all
// regressed: 3-phase staging, global-direct weights, tail de-barriering,
// and 512-thread scaling each broke the allocator's pin schedule. Do not
// touch this kernel's structure.
// Buffer layout:
//   A1: w2 k0-4 chunks 0..2559 | A2: w2 k5-8 chunks 0..2047
//   B : w3 chunks 0..2047 | mid shorts 16384..20991 (pitch 72)
// ---------------------------------------------------------------------------
__global__ __launch_bounds__(256, 2) void conv23_kernel(
    const float* __restrict__ feat, const int* __restrict__ nbr,
    const unsigned short* __restrict__ out1, const unsigned short* __restrict__ w2t,
    const float* __restrict__ b2, const unsigned short* __restrict__ w3t,
    const float* __restrict__ b3, float* __restrict__ out, int N)
{
    __shared__ __align__(16) unsigned short sWB[21504];      // 43008 B
    __shared__ int sNbr[64 * KOFF];                          // 2304 B

    int t = threadIdx.x;
    int wave = t >> 6;
    int lane = t & 63;
    int l15 = lane & 15;
    int quad = lane >> 4;
    int rt = wave * 16 + l15;
    int site = blockIdx.x * 64 + rt;
    int sitec = site < N ? site : (N - 1);

    bf16x8* sWBc = reinterpret_cast<bf16x8*>(sWB);
    const bf16x8* w2c = reinterpret_cast<const bf16x8*>(w2t);

    // ---- A1 stage: w2 k=0..4, 2560 chunks / 256 thr = 10 each ----
#pragma unroll
    for (int it = 0; it < 10; ++it) {
        int s = it * 256 + t;
        int l = s & 15, ct = (s >> 4) & 3, q = (s >> 6) & 3, kk = (s >> 8) & 1, k = s >> 9;
        sWBc[s] = w2c[k * 512 + (ct * 16 + l) * 8 + kk * 4 + q];
    }
#pragma unroll
    for (int i = 0; i < 3; ++i) {
        int j = i * 256 + t;
        if (j < 64 * KOFF) {
            int g = blockIdx.x * 64 * KOFF + j;
            sNbr[j] = (g < N * KOFF) ? nbr[g] : N;
        }
    }
    __syncthreads();                                         // B1

    int nb[KOFF];
#pragma unroll
    for (int k = 0; k < KOFF; ++k) nb[k] = sNbr[rt * KOFF + k];

    // ---- pin 18 gathers ----
    bf16x8 ga[KOFF][2];
#pragma unroll
    for (int k = 0; k < KOFF; ++k) {
        const bf16x8* pg = reinterpret_cast<const bf16x8*>(out1 + (size_t)nb[k] * C_MID + quad * 8);
        ga[k][0] = pg[0];
        ga[k][1] = pg[4];
    }
    __builtin_amdgcn_sched_barrier(0);

    f32x4 acc2[4] = {};
#pragma unroll
    for (int k = 0; k < 5; ++k) {
#pragma unroll
        for (int kk = 0; kk < 2; ++kk) {
#pragma unroll
            for (int ct = 0; ct < 4; ++ct) {
                bf16x8 fa = sWBc[((k * 2 + kk) * 4 + quad) * 64 + ct * 16 + l15];
                acc2[ct] = __builtin_amdgcn_mfma_f32_16x16x32_bf16(fa, ga[k][kk], acc2[ct], 0, 0, 0);
            }
        }
    }
    __syncthreads();                                         // B2: w2 part1 read done

    // ---- A2 stage: w2 k=5..8 overlaid into chunks 0..2047 ----
#pragma unroll
    for (int it = 0; it < 8; ++it) {
        int s = it * 256 + t;
        int l = s & 15, ct = (s >> 4) & 3, q = (s >> 6) & 3, kk = (s >> 8) & 1, k2 = s >> 9;
        sWBc[s] = w2c[(5 + k2) * 512 + (ct * 16 + l) * 8 + kk * 4 + q];
    }
    __syncthreads();                                         // B3
#pragma unroll
    for (int k = 5; k < KOFF; ++k) {
        int kloc = k - 5;
#pragma unroll
        for (int kk = 0; kk < 2; ++kk) {
#pragma unroll
            for (int ct = 0; ct < 4; ++ct) {
                bf16x8 fa = sWBc[((kloc * 2 + kk) * 4 + quad) * 64 + ct * 16 + l15];
                acc2[ct] = __builtin_amdgcn_mfma_f32_16x16x32_bf16(fa, ga[k][kk], acc2[ct], 0, 0, 0);
            }
        }
    }
    // ga dead — pin rf now (drains during staging + barrier)
    float4v rf[16];
#pragma unroll
    for (int c2 = 0; c2 < 16; ++c2)
        rf[c2] = *reinterpret_cast<const float4v*>(
            feat + (size_t)sitec * C_IN + c2 * 16 + quad * 4);
    __builtin_amdgcn_sched_barrier(0);
    __syncthreads();                                         // B4: w2 part2 read done

    // ---- phase B: mid (pitch 72) at shorts 16384..20991; w3 chunks 0..2047 ----
    unsigned short* mid = &sWB[16384];
#pragma unroll
    for (int ct = 0; ct < 4; ++ct) {
        float4v bb = *reinterpret_cast<const float4v*>(b2 + ct * 16 + quad * 4);
        union { unsigned short s[4]; short4v v; } o;
#pragma unroll
        for (int reg = 0; reg < 4; ++reg)
            o.s[reg] = f2bf(fmaxf(acc2[ct][reg] + bb[reg], 0.f));
        *reinterpret_cast<short4v*>(&mid[rt * 72 + ct * 16 + quad * 4]) = o.v;
    }
    const bf16x8* w3c = reinterpret_cast<const bf16x8*>(w3t);
#pragma unroll
    for (int it = 0; it < 8; ++it) {
        int s = it * 256 + t;
        int l = s & 15, c2 = (s >> 4) & 15, q = (s >> 8) & 3, kk = (s >> 10) & 1;
        sWBc[s] = w3c[(c2 * 16 + l) * 8 + kk * 4 + q];
    }
    __syncthreads();                                         // B5 (cross-lane LDS RAW)

    f32x4 acc3[16] = {};
#pragma unroll
    for (int kk = 0; kk < 2; ++kk) {
        bf16x8 fb = *reinterpret_cast<const bf16x8*>(
            &mid[rt * 72 + kk * 32 + quad * 8]);
#pragma unroll
        for (int c2 = 0; c2 < 16; ++c2) {
            bf16x8 fa = sWBc[((kk * 4 + quad) * 16 + c2) * 16 + l15];
            acc3[c2] = __builtin_amdgcn_mfma_f32_16x16x32_bf16(fa, fb, acc3[c2], 0, 0, 0);
        }
    }
    if (site < N) {
#pragma unroll
        for (int c2 = 0; c2 < 16; ++c2) {
            float4v bb = *reinterpret_cast<const float4v*>(b3 + c2 * 16 + quad * 4);
            float4v o;
#pragma unroll
            for (int reg = 0; reg < 4; ++reg)
                o[reg] = fmaxf(acc3[c2][reg] + bb[reg] + rf[c2][reg], 0.f);
            *reinterpret_cast<float4v*>(out + (size_t)site * C_IN + c2 * 16 + quad * 4) = o;
        }
    }
}

extern "C" void kernel_launch(void* const* d_in, const int* in_sizes, int n_in,
                              void* d_out, int out_size, void* d_ws, size_t ws_size,
                              hipStream_t stream) {
    const float* feat = (const float*)d_in[0];
    const int*   nbr  = (const int*)d_in[1];
    const float* w1   = (const float*)d_in[2];
    const float* s1   = (const float*)d_in[3];
    const float* b1   = (const float*)d_in[4];
    const float* w2   = (const float*)d_in[5];
    const float* s2   = (const float*)d_in[6];
    const float* b2   = (const float*)d_in[7];
    const float* w3   = (const float*)d_in[8];
    const float* s3   = (const float*)d_in[9];
    const float* b3   = (const float*)d_in[10];
    float* out = (float*)d_out;
    int N = in_sizes[0] / C_IN;

    char* ws = (char*)d_ws;
    unsigned short* w1t  = (unsigned short*)(ws);                    // 32768 B
    unsigned short* w2t  = (unsigned short*)(ws + 32768);            // 73728 B
    unsigned short* w3t  = (unsigned short*)(ws + 32768 + 73728);    // 32768 B
    unsigned short* out1 = (unsigned short*)(ws + 139264);           // (N+1)*64*2 B

    prep_kernel<<<80, 256, 0, stream>>>(w1, s1, w2, s2, w3, s3, w1t, w2t, w3t,
                                        out1 + (size_t)N * C_MID);
    int nblk1 = (N + 127) / 128;
    conv1_kernel<<<nblk1, 512, 0, stream>>>(feat, w1t, b1, out1, N);
    int nblk23 = (N + 63) / 64;
    conv23_kernel<<<nblk23, 256, 0, stream>>>(feat, nbr, out1, w2t, b2, w3t, b3, out, N);
}

// Round 9
// 259.397 us; speedup vs baseline: 1.0537x; 1.0083x over previous
//
#include <hip/hip_runtime.h>
#include <stdint.h>

#define C_IN 256
#define C_MID 64
#define KOFF 9

typedef __attribute__((ext_vector_type(8))) short bf16x8;   // 8 bf16 = 4 VGPRs
typedef __attribute__((ext_vector_type(4))) short short4v;  // 8 B packed bf16x4
typedef __attribute__((ext_vector_type(4))) float f32x4;    // MFMA C/D
typedef __attribute__((ext_vector_type(4))) float float4v;

// fp32 -> bf16 round-to-nearest-even
__device__ inline unsigned short f2bf(float f) {
    union { float f; unsigned u; } x; x.f = f;
    unsigned r = x.u + 0x7FFFu + ((x.u >> 16) & 1u);
    return (unsigned short)(r >> 16);
}

// ---------------------------------------------------------------------------
// prep (unchanged):
//   w1t[n][k] = bf16(w1[k][n] * s1[n])          [64][256]   16384 shorts
//   w2t[k][d][c] = bf16(w2[k][c][d] * s2[d])    [9][64][64] 36864 shorts
//   w3t[e][c] = bf16(w3[c][e] * s3[e])          [256][64]   16384 shorts
// ---------------------------------------------------------------------------
__global__ void prep_kernel(const float* __restrict__ w1, const float* __restrict__ s1,
                            const float* __restrict__ w2, const float* __restrict__ s2,
                            const float* __restrict__ w3, const float* __restrict__ s3,
                            unsigned short* __restrict__ w1t,
                            unsigned short* __restrict__ w2t,
                            unsigned short* __restrict__ w3t,
                            unsigned short* __restrict__ zrow) {
    int tid = blockIdx.x * blockDim.x + threadIdx.x;
    int stride = gridDim.x * blockDim.x;
    for (int i = tid; i < C_MID * C_IN; i += stride) {
        int n = i / C_IN, k = i % C_IN;
        w1t[i] = f2bf(w1[k * C_MID + n] * s1[n]);
    }
    for (int i = tid; i < KOFF * C_MID * C_MID; i += stride) {
        int k = i / (C_MID * C_MID);
        int r = i % (C_MID * C_MID);
        int d = r / C_MID, c = r % C_MID;
        w2t[i] = f2bf(w2[(k * C_MID + c) * C_MID + d] * s2[d]);
    }
    for (int i = tid; i < C_IN * C_MID; i += stride) {
        int e = i / C_MID, c = i % C_MID;
        w3t[i] = f2bf(w3[c * C_IN + e] * s3[e]);
    }
    for (int i = tid; i < C_MID; i += stride) zrow[i] = 0;
}

// ---------------------------------------------------------------------------
// conv1 v12: persistent-weights grid-stride. 1024 blocks (4/CU, max LDS
// residency), stage w1 ONCE per block, ONE barrier ever, then loop ~1.5
// site-tiles with the v4-proven per-tile dataflow (two pinned 8xfloat4
// groups -> 32 MFMAs -> store). Tile t+1's loads issue with no intervening
// barrier while tile t's MFMAs drain. Per-tile peak live regs unchanged
// (~95-100 <= 128 cap) — no pin-demotion risk.
// ---------------------------------------------------------------------------
__global__ __launch_bounds__(256, 4) void conv1_kernel(
    const float* __restrict__ feat, const unsigned short* __restrict__ w1t,
    const float* __restrict__ b1, unsigned short* __restrict__ out1,
    int N, int ntiles)
{
    __shared__ __align__(16) unsigned short sW1[16384];      // 32768 B

    int t = threadIdx.x;
    int wave = t >> 6;
    int lane = t & 63;
    int l15 = lane & 15;
    int quad = lane >> 4;

    const bf16x8* w1c = reinterpret_cast<const bf16x8*>(w1t);
    bf16x8* sW1c = reinterpret_cast<bf16x8*>(sW1);
#pragma unroll
    for (int it = 0; it < 8; ++it) {
        int s = it * 256 + t;
        int l = s & 15, ct = (s >> 4) & 3, q = (s >> 6) & 3, kk = s >> 8;
        sW1c[s] = w1c[(ct * 16 + l) * 32 + kk * 4 + q];
    }
    __syncthreads();                                         // only barrier

    for (int tile = blockIdx.x; tile < ntiles; tile += gridDim.x) {
        int site = tile * 64 + wave * 16 + l15;
        int sitec = site < N ? site : (N - 1);

        // ---- pin group 0: kk = 0..3 (8 float4 = 32 regs) ----
        float4v fr0[8];
#pragma unroll
        for (int kk = 0; kk < 4; ++kk) {
            const float4v* p = reinterpret_cast<const float4v*>(
                feat + (size_t)sitec * C_IN + kk * 32 + quad * 8);
            fr0[kk * 2] = p[0];
            fr0[kk * 2 + 1] = p[1];
        }
        __builtin_amdgcn_sched_barrier(0);

        // ---- pin group 1: kk = 4..7 (in flight during group-0 compute) ----
        float4v fr1[8];
#pragma unroll
        for (int kk = 0; kk < 4; ++kk) {
            const float4v* p = reinterpret_cast<const float4v*>(
                feat + (size_t)sitec * C_IN + (kk + 4) * 32 + quad * 8);
            fr1[kk * 2] = p[0];
            fr1[kk * 2 + 1] = p[1];
        }
        __builtin_amdgcn_sched_barrier(0);

        f32x4 acc[4] = {};
#pragma unroll
        for (int kk = 0; kk < 4; ++kk) {
            union { unsigned short s[8]; bf16x8 v; } ua;
#pragma unroll
            for (int j = 0; j < 4; ++j) {
                ua.s[j] = f2bf(fr0[kk * 2][j]);
                ua.s[4 + j] = f2bf(fr0[kk * 2 + 1][j]);
            }
#pragma unroll
            for (int ct = 0; ct < 4; ++ct) {
                bf16x8 fa = sW1c[((kk * 4 + quad) * 4 + ct) * 16 + l15];
                acc[ct] = __builtin_amdgcn_mfma_f32_16x16x32_bf16(fa, ua.v, acc[ct], 0, 0, 0);
            }
        }
#pragma unroll
        for (int kk = 0; kk < 4; ++kk) {
            union { unsigned short s[8]; bf16x8 v; } ua;
#pragma unroll
            for (int j = 0; j < 4; ++j) {
                ua.s[j] = f2bf(fr1[kk * 2][j]);
                ua.s[4 + j] = f2bf(fr1[kk * 2 + 1][j]);
            }
#pragma unroll
            for (int ct = 0; ct < 4; ++ct) {
                bf16x8 fa = sW1c[(((kk + 4) * 4 + quad) * 4 + ct) * 16 + l15];
                acc[ct] = __builtin_amdgcn_mfma_f32_16x16x32_bf16(fa, ua.v, acc[ct], 0, 0, 0);
            }
        }
        if (site < N) {
#pragma unroll
            for (int ct = 0; ct < 4; ++ct) {
                float4v bb = *reinterpret_cast<const float4v*>(b1 + ct * 16 + quad * 4);
                union { unsigned short s[4]; short4v v; } o;
#pragma unroll
                for (int reg = 0; reg < 4; ++reg)
                    o.s[reg] = f2bf(fmaxf(acc[ct][reg] + bb[reg], 0.f));
                *reinterpret_cast<short4v*>(out1 + (size_t)site * C_MID + ct * 16 + quad * 4) = o.v;
            }
        }
    }
}

// ---------------------------------------------------------------------------
// conv23 — R0 BYTE-EXACT (74.5 µs proven; VGPR-84 build). v5/v8/v9/v10 all
// regressed: 3-phase staging, global-direct weights, tail de-barriering,
// and 512-thread scaling each broke the allocator's pin schedule. Do not
// touch this kernel's structure.
// Buffer layout:
//   A1: w2 k0-4 chunks 0..2559 | A2: w2 k5-8 chunks 0..2047
//   B : w3 chunks 0..2047 | mid shorts 16384..20991 (pitch 72)
// ---------------------------------------------------------------------------
__global__ __launch_bounds__(256, 2) void conv23_kernel(
    const float* __restrict__ feat, const int* __restrict__ nbr,
    const unsigned short* __restrict__ out1, const unsigned short* __restrict__ w2t,
    const float* __restrict__ b2, const unsigned short* __restrict__ w3t,
    const float* __restrict__ b3, float* __restrict__ out, int N)
{
    __shared__ __align__(16) unsigned short sWB[21504];      // 43008 B
    __shared__ int sNbr[64 * KOFF];                          // 2304 B

    int t = threadIdx.x;
    int wave = t >> 6;
    int lane = t & 63;
    int l15 = lane & 15;
    int quad = lane >> 4;
    int rt = wave * 16 + l15;
    int site = blockIdx.x * 64 + rt;
    int sitec = site < N ? site : (N - 1);

    bf16x8* sWBc = reinterpret_cast<bf16x8*>(sWB);
    const bf16x8* w2c = reinterpret_cast<const bf16x8*>(w2t);

    // ---- A1 stage: w2 k=0..4, 2560 chunks / 256 thr = 10 each ----
#pragma unroll
    for (int it = 0; it < 10; ++it) {
        int s = it * 256 + t;
        int l = s & 15, ct = (s >> 4) & 3, q = (s >> 6) & 3, kk = (s >> 8) & 1, k = s >> 9;
        sWBc[s] = w2c[k * 512 + (ct * 16 + l) * 8 + kk * 4 + q];
    }
#pragma unroll
    for (int i = 0; i < 3; ++i) {
        int j = i * 256 + t;
        if (j < 64 * KOFF) {
            int g = blockIdx.x * 64 * KOFF + j;
            sNbr[j] = (g < N * KOFF) ? nbr[g] : N;
        }
    }
    __syncthreads();                                         // B1

    int nb[KOFF];
#pragma unroll
    for (int k = 0; k < KOFF; ++k) nb[k] = sNbr[rt * KOFF + k];

    // ---- pin 18 gathers ----
    bf16x8 ga[KOFF][2];
#pragma unroll
    for (int k = 0; k < KOFF; ++k) {
        const bf16x8* pg = reinterpret_cast<const bf16x8*>(out1 + (size_t)nb[k] * C_MID + quad * 8);
        ga[k][0] = pg[0];
        ga[k][1] = pg[4];
    }
    __builtin_amdgcn_sched_barrier(0);

    f32x4 acc2[4] = {};
#pragma unroll
    for (int k = 0; k < 5; ++k) {
#pragma unroll
        for (int kk = 0; kk < 2; ++kk) {
#pragma unroll
            for (int ct = 0; ct < 4; ++ct) {
                bf16x8 fa = sWBc[((k * 2 + kk) * 4 + quad) * 64 + ct * 16 + l15];
                acc2[ct] = __builtin_amdgcn_mfma_f32_16x16x32_bf16(fa, ga[k][kk], acc2[ct], 0, 0, 0);
            }
        }
    }
    __syncthreads();                                         // B2: w2 part1 read done

    // ---- A2 stage: w2 k=5..8 overlaid into chunks 0..2047 ----
#pragma unroll
    for (int it = 0; it < 8; ++it) {
        int s = it * 256 + t;
        int l = s & 15, ct = (s >> 4) & 3, q = (s >> 6) & 3, kk = (s >> 8) & 1, k2 = s >> 9;
        sWBc[s] = w2c[(5 + k2) * 512 + (ct * 16 + l) * 8 + kk * 4 + q];
    }
    __syncthreads();                                         // B3
#pragma unroll
    for (int k = 5; k < KOFF; ++k) {
        int kloc = k - 5;
#pragma unroll
        for (int kk = 0; kk < 2; ++kk) {
#pragma unroll
            for (int ct = 0; ct < 4; ++ct) {
                bf16x8 fa = sWBc[((kloc * 2 + kk) * 4 + quad) * 64 + ct * 16 + l15];
                acc2[ct] = __builtin_amdgcn_mfma_f32_16x16x32_bf16(fa, ga[k][kk], acc2[ct], 0, 0, 0);
            }
        }
    }
    // ga dead — pin rf now (drains during staging + barrier)
    float4v rf[16];
#pragma unroll
    for (int c2 = 0; c2 < 16; ++c2)
        rf[c2] = *reinterpret_cast<const float4v*>(
            feat + (size_t)sitec * C_IN + c2 * 16 + quad * 4);
    __builtin_amdgcn_sched_barrier(0);
    __syncthreads();                                         // B4: w2 part2 read done

    // ---- phase B: mid (pitch 72) at shorts 16384..20991; w3 chunks 0..2047 ----
    unsigned short* mid = &sWB[16384];
#pragma unroll
    for (int ct = 0; ct < 4; ++ct) {
        float4v bb = *reinterpret_cast<const float4v*>(b2 + ct * 16 + quad * 4);
        union { unsigned short s[4]; short4v v; } o;
#pragma unroll
        for (int reg = 0; reg < 4; ++reg)
            o.s[reg] = f2bf(fmaxf(acc2[ct][reg] + bb[reg], 0.f));
        *reinterpret_cast<short4v*>(&mid[rt * 72 + ct * 16 + quad * 4]) = o.v;
    }
    const bf16x8* w3c = reinterpret_cast<const bf16x8*>(w3t);
#pragma unroll
    for (int it = 0; it < 8; ++it) {
        int s = it * 256 + t;
        int l = s & 15, c2 = (s >> 4) & 15, q = (s >> 8) & 3, kk = (s >> 10) & 1;
        sWBc[s] = w3c[(c2 * 16 + l) * 8 + kk * 4 + q];
    }
    __syncthreads();                                         // B5 (cross-lane LDS RAW)

    f32x4 acc3[16] = {};
#pragma unroll
    for (int kk = 0; kk < 2; ++kk) {
        bf16x8 fb = *reinterpret_cast<const bf16x8*>(
            &mid[rt * 72 + kk * 32 + quad * 8]);
#pragma unroll
        for (int c2 = 0; c2 < 16; ++c2) {
            bf16x8 fa = sWBc[((kk * 4 + quad) * 16 + c2) * 16 + l15];
            acc3[c2] = __builtin_amdgcn_mfma_f32_16x16x32_bf16(fa, fb, acc3[c2], 0, 0, 0);
        }
    }
    if (site < N) {
#pragma unroll
        for (int c2 = 0; c2 < 16; ++c2) {
            float4v bb = *reinterpret_cast<const float4v*>(b3 + c2 * 16 + quad * 4);
            float4v o;
#pragma unroll
            for (int reg = 0; reg < 4; ++reg)
                o[reg] = fmaxf(acc3[c2][reg] + bb[reg] + rf[c2][reg], 0.f);
            *reinterpret_cast<float4v*>(out + (size_t)site * C_IN + c2 * 16 + quad * 4) = o;
        }
    }
}

extern "C" void kernel_launch(void* const* d_in, const int* in_sizes, int n_in,
                              void* d_out, int out_size, void* d_ws, size_t ws_size,
                              hipStream_t stream) {
    const float* feat = (const float*)d_in[0];
    const int*   nbr  = (const int*)d_in[1];
    const float* w1   = (const float*)d_in[2];
    const float* s1   = (const float*)d_in[3];
    const float* b1   = (const float*)d_in[4];
    const float* w2   = (const float*)d_in[5];
    const float* s2   = (const float*)d_in[6];
    const float* b2   = (const float*)d_in[7];
    const float* w3   = (const float*)d_in[8];
    const float* s3   = (const float*)d_in[9];
    const float* b3   = (const float*)d_in[10];
    float* out = (float*)d_out;
    int N = in_sizes[0] / C_IN;

    char* ws = (char*)d_ws;
    unsigned short* w1t  = (unsigned short*)(ws);                    // 32768 B
    unsigned short* w2t  = (unsigned short*)(ws + 32768);            // 73728 B
    unsigned short* w3t  = (unsigned short*)(ws + 32768 + 73728);    // 32768 B
    unsigned short* out1 = (unsigned short*)(ws + 139264);           // (N+1)*64*2 B

    prep_kernel<<<80, 256, 0, stream>>>(w1, s1, w2, s2, w3, s3, w1t, w2t, w3t,
                                        out1 + (size_t)N * C_MID);
    int ntiles = (N + 63) / 64;
    int nblk1 = ntiles < 1024 ? ntiles : 1024;
    conv1_kernel<<<nblk1, 256, 0, stream>>>(feat, w1t, b1, out1, N, ntiles);
    conv23_kernel<<<ntiles, 256, 0, stream>>>(feat, nbr, out1, w2t, b2, w3t, b3, out, N);
}

// Round 10
// 259.189 us; speedup vs baseline: 1.0546x; 1.0008x over previous
//
#include <hip/hip_runtime.h>
#include <stdint.h>

#define C_IN 256
#define C_MID 64
#define KOFF 9

typedef __attribute__((ext_vector_type(8))) short bf16x8;   // 8 bf16 = 4 VGPRs
typedef __attribute__((ext_vector_type(4))) short short4v;  // 8 B packed bf16x4
typedef __attribute__((ext_vector_type(4))) float f32x4;    // MFMA C/D
typedef __attribute__((ext_vector_type(4))) float float4v;

// fp32 -> bf16 round-to-nearest-even
__device__ inline unsigned short f2bf(float f) {
    union { float f; unsigned u; } x; x.f = f;
    unsigned r = x.u + 0x7FFFu + ((x.u >> 16) & 1u);
    return (unsigned short)(r >> 16);
}

// ---------------------------------------------------------------------------
// prep (unchanged):
//   w1t[n][k] = bf16(w1[k][n] * s1[n])          [64][256]   16384 shorts
//   w2t[k][d][c] = bf16(w2[k][c][d] * s2[d])    [9][64][64] 36864 shorts
//   w3t[e][c] = bf16(w3[c][e] * s3[e])          [256][64]   16384 shorts
// ---------------------------------------------------------------------------
__global__ void prep_kernel(const float* __restrict__ w1, const float* __restrict__ s1,
                            const float* __restrict__ w2, const float* __restrict__ s2,
                            const float* __restrict__ w3, const float* __restrict__ s3,
                            unsigned short* __restrict__ w1t,
                            unsigned short* __restrict__ w2t,
                            unsigned short* __restrict__ w3t,
                            unsigned short* __restrict__ zrow) {
    int tid = blockIdx.x * blockDim.x + threadIdx.x;
    int stride = gridDim.x * blockDim.x;
    for (int i = tid; i < C_MID * C_IN; i += stride) {
        int n = i / C_IN, k = i % C_IN;
        w1t[i] = f2bf(w1[k * C_MID + n] * s1[n]);
    }
    for (int i = tid; i < KOFF * C_MID * C_MID; i += stride) {
        int k = i / (C_MID * C_MID);
        int r = i % (C_MID * C_MID);
        int d = r / C_MID, c = r % C_MID;
        w2t[i] = f2bf(w2[(k * C_MID + c) * C_MID + d] * s2[d]);
    }
    for (int i = tid; i < C_IN * C_MID; i += stride) {
        int e = i / C_MID, c = i % C_MID;
        w3t[i] = f2bf(w3[c * C_IN + e] * s3[e]);
    }
    for (int i = tid; i < C_MID; i += stride) zrow[i] = 0;
}

// ---------------------------------------------------------------------------
// conv1 v12 (R9-proven, part of the 259.4 µs best): persistent-weights
// grid-stride. 1024 blocks, stage w1 ONCE per block, ONE barrier ever, then
// loop site-tiles with the v4-proven per-tile dataflow. Unchanged (control).
// ---------------------------------------------------------------------------
__global__ __launch_bounds__(256, 4) void conv1_kernel(
    const float* __restrict__ feat, const unsigned short* __restrict__ w1t,
    const float* __restrict__ b1, unsigned short* __restrict__ out1,
    int N, int ntiles)
{
    __shared__ __align__(16) unsigned short sW1[16384];      // 32768 B

    int t = threadIdx.x;
    int wave = t >> 6;
    int lane = t & 63;
    int l15 = lane & 15;
    int quad = lane >> 4;

    const bf16x8* w1c = reinterpret_cast<const bf16x8*>(w1t);
    bf16x8* sW1c = reinterpret_cast<bf16x8*>(sW1);
#pragma unroll
    for (int it = 0; it < 8; ++it) {
        int s = it * 256 + t;
        int l = s & 15, ct = (s >> 4) & 3, q = (s >> 6) & 3, kk = s >> 8;
        sW1c[s] = w1c[(ct * 16 + l) * 32 + kk * 4 + q];
    }
    __syncthreads();                                         // only barrier

    for (int tile = blockIdx.x; tile < ntiles; tile += gridDim.x) {
        int site = tile * 64 + wave * 16 + l15;
        int sitec = site < N ? site : (N - 1);

        // ---- pin group 0: kk = 0..3 (8 float4 = 32 regs) ----
        float4v fr0[8];
#pragma unroll
        for (int kk = 0; kk < 4; ++kk) {
            const float4v* p = reinterpret_cast<const float4v*>(
                feat + (size_t)sitec * C_IN + kk * 32 + quad * 8);
            fr0[kk * 2] = p[0];
            fr0[kk * 2 + 1] = p[1];
        }
        __builtin_amdgcn_sched_barrier(0);

        // ---- pin group 1: kk = 4..7 (in flight during group-0 compute) ----
        float4v fr1[8];
#pragma unroll
        for (int kk = 0; kk < 4; ++kk) {
            const float4v* p = reinterpret_cast<const float4v*>(
                feat + (size_t)sitec * C_IN + (kk + 4) * 32 + quad * 8);
            fr1[kk * 2] = p[0];
            fr1[kk * 2 + 1] = p[1];
        }
        __builtin_amdgcn_sched_barrier(0);

        f32x4 acc[4] = {};
#pragma unroll
        for (int kk = 0; kk < 4; ++kk) {
            union { unsigned short s[8]; bf16x8 v; } ua;
#pragma unroll
            for (int j = 0; j < 4; ++j) {
                ua.s[j] = f2bf(fr0[kk * 2][j]);
                ua.s[4 + j] = f2bf(fr0[kk * 2 + 1][j]);
            }
#pragma unroll
            for (int ct = 0; ct < 4; ++ct) {
                bf16x8 fa = sW1c[((kk * 4 + quad) * 4 + ct) * 16 + l15];
                acc[ct] = __builtin_amdgcn_mfma_f32_16x16x32_bf16(fa, ua.v, acc[ct], 0, 0, 0);
            }
        }
#pragma unroll
        for (int kk = 0; kk < 4; ++kk) {
            union { unsigned short s[8]; bf16x8 v; } ua;
#pragma unroll
            for (int j = 0; j < 4; ++j) {
                ua.s[j] = f2bf(fr1[kk * 2][j]);
                ua.s[4 + j] = f2bf(fr1[kk * 2 + 1][j]);
            }
#pragma unroll
            for (int ct = 0; ct < 4; ++ct) {
                bf16x8 fa = sW1c[(((kk + 4) * 4 + quad) * 4 + ct) * 16 + l15];
                acc[ct] = __builtin_amdgcn_mfma_f32_16x16x32_bf16(fa, ua.v, acc[ct], 0, 0, 0);
            }
        }
        if (site < N) {
#pragma unroll
            for (int ct = 0; ct < 4; ++ct) {
                float4v bb = *reinterpret_cast<const float4v*>(b1 + ct * 16 + quad * 4);
                union { unsigned short s[4]; short4v v; } o;
#pragma unroll
                for (int reg = 0; reg < 4; ++reg)
                    o.s[reg] = f2bf(fmaxf(acc[ct][reg] + bb[reg], 0.f));
                *reinterpret_cast<short4v*>(out1 + (size_t)site * C_MID + ct * 16 + quad * 4) = o.v;
            }
        }
    }
}

// ---------------------------------------------------------------------------
// conv23 v13: R0 structure BYTE-EXACT (the proven 74.5 µs / VGPR-84 build;
// 6/6 structural edits regressed — do not touch the schedule). ONLY change:
// cache-policy bits. rf loads (streaming feat, ~102 MB) and out stores
// (~102 MB) are NON-TEMPORAL so the ~200 MB/kernel streaming mix stops
// cycling the 4 MiB per-XCD L2 — leaving L2 to retain out1's hot gather
// set (12.8 MB). Gathers themselves stay cached. Same instructions, same
// order, same registers — only the nt bit.
// Buffer layout:
//   A1: w2 k0-4 chunks 0..2559 | A2: w2 k5-8 chunks 0..2047
//   B : w3 chunks 0..2047 | mid shorts 16384..20991 (pitch 72)
// ---------------------------------------------------------------------------
__global__ __launch_bounds__(256, 2) void conv23_kernel(
    const float* __restrict__ feat, const int* __restrict__ nbr,
    const unsigned short* __restrict__ out1, const unsigned short* __restrict__ w2t,
    const float* __restrict__ b2, const unsigned short* __restrict__ w3t,
    const float* __restrict__ b3, float* __restrict__ out, int N)
{
    __shared__ __align__(16) unsigned short sWB[21504];      // 43008 B
    __shared__ int sNbr[64 * KOFF];                          // 2304 B

    int t = threadIdx.x;
    int wave = t >> 6;
    int lane = t & 63;
    int l15 = lane & 15;
    int quad = lane >> 4;
    int rt = wave * 16 + l15;
    int site = blockIdx.x * 64 + rt;
    int sitec = site < N ? site : (N - 1);

    bf16x8* sWBc = reinterpret_cast<bf16x8*>(sWB);
    const bf16x8* w2c = reinterpret_cast<const bf16x8*>(w2t);

    // ---- A1 stage: w2 k=0..4, 2560 chunks / 256 thr = 10 each ----
#pragma unroll
    for (int it = 0; it < 10; ++it) {
        int s = it * 256 + t;
        int l = s & 15, ct = (s >> 4) & 3, q = (s >> 6) & 3, kk = (s >> 8) & 1, k = s >> 9;
        sWBc[s] = w2c[k * 512 + (ct * 16 + l) * 8 + kk * 4 + q];
    }
#pragma unroll
    for (int i = 0; i < 3; ++i) {
        int j = i * 256 + t;
        if (j < 64 * KOFF) {
            int g = blockIdx.x * 64 * KOFF + j;
            sNbr[j] = (g < N * KOFF) ? nbr[g] : N;
        }
    }
    __syncthreads();                                         // B1

    int nb[KOFF];
#pragma unroll
    for (int k = 0; k < KOFF; ++k) nb[k] = sNbr[rt * KOFF + k];

    // ---- pin 18 gathers (cached — these WANT L2 residency) ----
    bf16x8 ga[KOFF][2];
#pragma unroll
    for (int k = 0; k < KOFF; ++k) {
        const bf16x8* pg = reinterpret_cast<const bf16x8*>(out1 + (size_t)nb[k] * C_MID + quad * 8);
        ga[k][0] = pg[0];
        ga[k][1] = pg[4];
    }
    __builtin_amdgcn_sched_barrier(0);

    f32x4 acc2[4] = {};
#pragma unroll
    for (int k = 0; k < 5; ++k) {
#pragma unroll
        for (int kk = 0; kk < 2; ++kk) {
#pragma unroll
            for (int ct = 0; ct < 4; ++ct) {
                bf16x8 fa = sWBc[((k * 2 + kk) * 4 + quad) * 64 + ct * 16 + l15];
                acc2[ct] = __builtin_amdgcn_mfma_f32_16x16x32_bf16(fa, ga[k][kk], acc2[ct], 0, 0, 0);
            }
        }
    }
    __syncthreads();                                         // B2: w2 part1 read done

    // ---- A2 stage: w2 k=5..8 overlaid into chunks 0..2047 ----
#pragma unroll
    for (int it = 0; it < 8; ++it) {
        int s = it * 256 + t;
        int l = s & 15, ct = (s >> 4) & 3, q = (s >> 6) & 3, kk = (s >> 8) & 1, k2 = s >> 9;
        sWBc[s] = w2c[(5 + k2) * 512 + (ct * 16 + l) * 8 + kk * 4 + q];
    }
    __syncthreads();                                         // B3
#pragma unroll
    for (int k = 5; k < KOFF; ++k) {
        int kloc = k - 5;
#pragma unroll
        for (int kk = 0; kk < 2; ++kk) {
#pragma unroll
            for (int ct = 0; ct < 4; ++ct) {
                bf16x8 fa = sWBc[((kloc * 2 + kk) * 4 + quad) * 64 + ct * 16 + l15];
                acc2[ct] = __builtin_amdgcn_mfma_f32_16x16x32_bf16(fa, ga[k][kk], acc2[ct], 0, 0, 0);
            }
        }
    }
    // ga dead — pin rf now (NON-TEMPORAL: streaming, read-once, keep out of L2)
    float4v rf[16];
#pragma unroll
    for (int c2 = 0; c2 < 16; ++c2)
        rf[c2] = __builtin_nontemporal_load(reinterpret_cast<const float4v*>(
            feat + (size_t)sitec * C_IN + c2 * 16 + quad * 4));
    __builtin_amdgcn_sched_barrier(0);
    __syncthreads();                                         // B4: w2 part2 read done

    // ---- phase B: mid (pitch 72) at shorts 16384..20991; w3 chunks 0..2047 ----
    unsigned short* mid = &sWB[16384];
#pragma unroll
    for (int ct = 0; ct < 4; ++ct) {
        float4v bb = *reinterpret_cast<const float4v*>(b2 + ct * 16 + quad * 4);
        union { unsigned short s[4]; short4v v; } o;
#pragma unroll
        for (int reg = 0; reg < 4; ++reg)
            o.s[reg] = f2bf(fmaxf(acc2[ct][reg] + bb[reg], 0.f));
        *reinterpret_cast<short4v*>(&mid[rt * 72 + ct * 16 + quad * 4]) = o.v;
    }
    const bf16x8* w3c = reinterpret_cast<const bf16x8*>(w3t);
#pragma unroll
    for (int it = 0; it < 8; ++it) {
        int s = it * 256 + t;
        int l = s & 15, c2 = (s >> 4) & 15, q = (s >> 8) & 3, kk = (s >> 10) & 1;
        sWBc[s] = w3c[(c2 * 16 + l) * 8 + kk * 4 + q];
    }
    __syncthreads();                                         // B5 (cross-lane LDS RAW)

    f32x4 acc3[16] = {};
#pragma unroll
    for (int kk = 0; kk < 2; ++kk) {
        bf16x8 fb = *reinterpret_cast<const bf16x8*>(
            &mid[rt * 72 + kk * 32 + quad * 8]);
#pragma unroll
        for (int c2 = 0; c2 < 16; ++c2) {
            bf16x8 fa = sWBc[((kk * 4 + quad) * 16 + c2) * 16 + l15];
            acc3[c2] = __builtin_amdgcn_mfma_f32_16x16x32_bf16(fa, fb, acc3[c2], 0, 0, 0);
        }
    }
    if (site < N) {
#pragma unroll
        for (int c2 = 0; c2 < 16; ++c2) {
            float4v bb = *reinterpret_cast<const float4v*>(b3 + c2 * 16 + quad * 4);
            float4v o;
#pragma unroll
            for (int reg = 0; reg < 4; ++reg)
                o[reg] = fmaxf(acc3[c2][reg] + bb[reg] + rf[c2][reg], 0.f);
            __builtin_nontemporal_store(o, reinterpret_cast<float4v*>(
                out + (size_t)site * C_IN + c2 * 16 + quad * 4));
        }
    }
}

extern "C" void kernel_launch(void* const* d_in, const int* in_sizes, int n_in,
                              void* d_out, int out_size, void* d_ws, size_t ws_size,
                              hipStream_t stream) {
    const float* feat = (const float*)d_in[0];
    const int*   nbr  = (const int*)d_in[1];
    const float* w1   = (const float*)d_in[2];
    const float* s1   = (const float*)d_in[3];
    const float* b1   = (const float*)d_in[4];
    const float* w2   = (const float*)d_in[5];
    const float* s2   = (const float*)d_in[6];
    const float* b2   = (const float*)d_in[7];
    const float* w3   = (const float*)d_in[8];
    const float* s3   = (const float*)d_in[9];
    const float* b3   = (const float*)d_in[10];
    float* out = (float*)d_out;
    int N = in_sizes[0] / C_IN;

    char* ws = (char*)d_ws;
    unsigned short* w1t  = (unsigned short*)(ws);                    // 32768 B
    unsigned short* w2t  = (unsigned short*)(ws + 32768);            // 73728 B
    unsigned short* w3t  = (unsigned short*)(ws + 32768 + 73728);    // 32768 B
    unsigned short* out1 = (unsigned short*)(ws + 139264);           // (N+1)*64*2 B

    prep_kernel<<<80, 256, 0, stream>>>(w1, s1, w2, s2, w3, s3, w1t, w2t, w3t,
                                        out1 + (size_t)N * C_MID);
    int ntiles = (N + 63) / 64;
    int nblk1 = ntiles < 1024 ? ntiles : 1024;
    conv1_kernel<<<nblk1, 256, 0, stream>>>(feat, w1t, b1, out1, N, ntiles);
    conv23_kernel<<<ntiles, 256, 0, stream>>>(feat, nbr, out1, w2t, b2, w3t, b3, out, N);
}